// Round 16
// baseline (538.764 us; speedup 1.0000x reference)
//
#include <hip/hip_runtime.h>

#define N_NODES  100000
#define N_EDGES  800000
#define ET       900000   // edges + self loops
#define N_GRAPHS 2000
#define IN_DIM   64
#define HID      32
#define HEADS    4
#define HF       128      // HEADS*HID
#define NEG_SLOPE 0.2f

typedef __attribute__((ext_vector_type(8))) short bf16x8;
typedef __attribute__((ext_vector_type(4))) float f32x4;

__device__ __forceinline__ float lrelu(float x) { return x > 0.f ? x : NEG_SLOPE * x; }
__device__ __forceinline__ float elu_f(float x) { return x > 0.f ? x : expm1f(x); }
// order-preserving float<->uint encode for atomicMax over signed floats
__device__ __forceinline__ unsigned fenc(float f) {
  unsigned u = __float_as_uint(f);
  return (u & 0x80000000u) ? ~u : (u | 0x80000000u);
}
__device__ __forceinline__ float fdec(unsigned e) {
  return __uint_as_float((e & 0x80000000u) ? (e ^ 0x80000000u) : ~e);
}
// round-to-nearest-even fp32 -> bf16 (bit trick)
__device__ __forceinline__ unsigned short bf16_rne(float f) {
  unsigned u = __float_as_uint(f);
  unsigned r = (u + 0x7fffu + ((u >> 16) & 1u)) >> 16;
  return (unsigned short)r;
}

// ---------------- CSR build ----------------
__global__ void k_count(const int* __restrict__ ei, int* __restrict__ deg) {
  int e = blockIdx.x * 256 + threadIdx.x;
  if (e >= ET) return;
  int d = (e < N_EDGES) ? ei[N_EDGES + e] : (e - N_EDGES);
  atomicAdd(&deg[d], 1);
}

__global__ void k_scan1(const int* __restrict__ deg, int* __restrict__ rs, int* __restrict__ bsums) {
  __shared__ int sd[256];
  int t = threadIdx.x;
  int i = blockIdx.x * 256 + t;
  int v = (i < N_NODES) ? deg[i] : 0;
  sd[t] = v; __syncthreads();
  for (int s = 1; s < 256; s <<= 1) {
    int tmp = (t >= s) ? sd[t - s] : 0; __syncthreads();
    sd[t] += tmp; __syncthreads();
  }
  if (i < N_NODES) rs[i] = sd[t] - v;
  if (t == 255) bsums[blockIdx.x] = sd[255];
}

__global__ void k_scan2(int* __restrict__ bsums, int nb) {
  __shared__ int sd[512];
  int t = threadIdx.x;
  int v = (t < nb) ? bsums[t] : 0;
  sd[t] = v; __syncthreads();
  for (int s = 1; s < 512; s <<= 1) {
    int tmp = (t >= s) ? sd[t - s] : 0; __syncthreads();
    sd[t] += tmp; __syncthreads();
  }
  if (t < nb) bsums[t] = sd[t] - v;
}

__global__ void k_scan3(int* __restrict__ rs, const int* __restrict__ bsums) {
  int i = blockIdx.x * 256 + threadIdx.x;
  if (i < N_NODES) rs[i] += bsums[blockIdx.x];
  if (i == 0) rs[N_NODES] = ET;
}

__global__ void k_fill(const int* __restrict__ ei, const int* __restrict__ rs,
                       int* __restrict__ fill, int* __restrict__ csr_src) {
  int e = blockIdx.x * 256 + threadIdx.x;
  if (e >= ET) return;
  int s, d;
  if (e < N_EDGES) { s = ei[e]; d = ei[N_EDGES + e]; }
  else             { s = e - N_EDGES; d = s; }
  int pos = atomicAdd(&fill[d], 1);
  csr_src[rs[d] + pos] = s;
}

// ---------------- weight prep: pack [W | W.a_src | W.a_dst | 0] (144 cols),
// split fp32 -> bf16 hi/lo, store in MFMA B-fragment layout [k/8][c][k&7] ----
template<int K>
__global__ void k_prep(const float* __restrict__ W, const float* __restrict__ as_,
                       const float* __restrict__ ad_,
                       unsigned short* __restrict__ Bh, unsigned short* __restrict__ Bl) {
  int idx = blockIdx.x * 256 + threadIdx.x;
  if (idx >= K * 144) return;
  int k = idx / 144, c = idx % 144;
  float v = 0.f;
  if (c < 128) {
    v = W[k * 128 + c];
  } else if (c < 136) {
    int h = (c - 128) & 3;
    const float* av = (c < 132) ? as_ : ad_;
    float s = 0.f;
    for (int f = 0; f < HID; ++f) s += W[k * 128 + h * HID + f] * av[h * HID + f];
    v = s;
  }
  unsigned short hi = bf16_rne(v);
  float hf = __uint_as_float((unsigned)hi << 16);
  unsigned short lo = bf16_rne(v - hf);
  size_t dst = ((size_t)(k >> 3) * 144 + c) * 8 + (k & 7);
  Bh[dst] = hi;
  Bl[dst] = lo;
}

// ---------------- MFMA GEMM (split-bf16) + fused attention cols + AS max ----
// 32-row wave tiles (R14 acc layout) + HALF-K B staging: 36.9 KB LDS ->
// 4 blocks/CU, 16 waves/CU for TLP latency hiding. Depth-1 A prefetch
// survives the restage barrier in registers. Epilogue bounces accumulators
// through LDS in two 64-row passes for full-line coalesced stores.
template<int K>
__global__ void __launch_bounds__(256, 4) k_gemm_attn(
    const float* __restrict__ X,
    const unsigned short* __restrict__ Bh, const unsigned short* __restrict__ Bl,
    float* __restrict__ H, float* __restrict__ AS, float* __restrict__ AD,
    unsigned* __restrict__ M4) {
  constexpr int KH = 64;                       // k-half
  __shared__ __align__(16) char smem[2 * KH * 144 * 2];   // 36,864 B
  short* sBh = (short*)smem;
  short* sBl = (short*)(smem + KH * 144 * 2);
  const int t = threadIdx.x;
  const int l = t & 63;
  const int w = t >> 6;
  const int m = l & 15;                 // A-row / B-col / D-col selector
  const int g = l >> 4;                 // k-group selector (8 k per group)
  const int row0 = blockIdx.x * 128 + w * 32;  // this wave's 32 rows
  const int row_a = row0 + m;           // tr=0 A row
  const int row_b = row0 + 16 + m;      // tr=1 A row

  f32x4 acc[2][9];
#pragma unroll
  for (int a = 0; a < 2; ++a)
#pragma unroll
    for (int b = 0; b < 9; ++b) acc[a][b] = (f32x4){0.f, 0.f, 0.f, 0.f};

  float4 pxa0, pxb0, pxa1, pxb1;        // prefetched A (2 row-tiles x 32B)
#define LOADA(kb)                                                              \
  {                                                                            \
    pxa0 = pxb0 = pxa1 = pxb1 = make_float4(0.f, 0.f, 0.f, 0.f);               \
    if (row_a < N_NODES) {                                                     \
      const float4* xp = (const float4*)&X[(size_t)row_a * K + (kb) + g * 8];  \
      pxa0 = xp[0]; pxb0 = xp[1];                                              \
    }                                                                          \
    if (row_b < N_NODES) {                                                     \
      const float4* xp = (const float4*)&X[(size_t)row_b * K + (kb) + g * 8];  \
      pxa1 = xp[0]; pxb1 = xp[1];                                              \
    }                                                                          \
  }

  LOADA(0);
  for (int h = 0; h < K / KH; ++h) {
    __syncthreads();                    // previous half's ds_reads complete
    for (int i = t; i < KH * 18; i += 256) {   // stage this half's B
      ((bf16x8*)sBh)[i] = ((const bf16x8*)Bh)[h * (KH * 18) + i];
      ((bf16x8*)sBl)[i] = ((const bf16x8*)Bl)[h * (KH * 18) + i];
    }
    __syncthreads();                    // LDS ready
#pragma unroll
    for (int cc = 0; cc < 2; ++cc) {    // two 32-k chunks per half
      int kb = h * KH + cc * 32;
      bf16x8 ahi[2], alo[2];
      {
        float xv0[8] = {pxa0.x, pxa0.y, pxa0.z, pxa0.w, pxb0.x, pxb0.y, pxb0.z, pxb0.w};
        float xv1[8] = {pxa1.x, pxa1.y, pxa1.z, pxa1.w, pxb1.x, pxb1.y, pxb1.z, pxb1.w};
#pragma unroll
        for (int j = 0; j < 8; ++j) {
          unsigned short h0 = bf16_rne(xv0[j]);
          ahi[0][j] = (short)h0;
          alo[0][j] = (short)bf16_rne(xv0[j] - __uint_as_float((unsigned)h0 << 16));
          unsigned short h1 = bf16_rne(xv1[j]);
          ahi[1][j] = (short)h1;
          alo[1][j] = (short)bf16_rne(xv1[j] - __uint_as_float((unsigned)h1 << 16));
        }
      }
      if (kb + 32 < K) LOADA(kb + 32);  // issue next chunk's loads now

      const int kfl = (cc * 4 + g) * 144;   // half-local fragment row
#pragma unroll
      for (int tc = 0; tc < 9; ++tc) {
        bf16x8 bh = *(const bf16x8*)(sBh + (kfl + tc * 16 + m) * 8);
        bf16x8 bl = *(const bf16x8*)(sBl + (kfl + tc * 16 + m) * 8);
#pragma unroll
        for (int tr = 0; tr < 2; ++tr) {
          acc[tr][tc] = __builtin_amdgcn_mfma_f32_16x16x32_bf16(ahi[tr], bh, acc[tr][tc], 0, 0, 0);
          acc[tr][tc] = __builtin_amdgcn_mfma_f32_16x16x32_bf16(ahi[tr], bl, acc[tr][tc], 0, 0, 0);
          acc[tr][tc] = __builtin_amdgcn_mfma_f32_16x16x32_bf16(alo[tr], bh, acc[tr][tc], 0, 0, 0);
        }
      }
    }
  }
#undef LOADA

  // per-head AS max from registers (lane l=g*16+m; fold over g via xor16/32)
  float vmax = -3.4e38f;
#pragma unroll
  for (int tr = 0; tr < 2; ++tr)
#pragma unroll
    for (int e = 0; e < 4; ++e) vmax = fmaxf(vmax, acc[tr][8][e]);
  vmax = fmaxf(vmax, __shfl_xor(vmax, 16));
  vmax = fmaxf(vmax, __shfl_xor(vmax, 32));
  if (g == 0 && m < 4) atomicMax(&M4[m], fenc(vmax));

  // ---- epilogue: two 64-row LDS-bounce passes (fits the 36.9 KB buffer) ---
  float* sF  = (float*)smem;            // [64][128] fp32
  float* sAS = sF + 64 * 128;           // [64][4]
  float* sAD = sAS + 64 * 4;            // [64][4]   total 34.8 KB
#pragma unroll
  for (int pass = 0; pass < 2; ++pass) {
    __syncthreads();                    // prior reads of smem complete
    if ((w >> 1) == pass) {             // waves 0,1 -> pass 0; waves 2,3 -> pass 1
      int rl0 = (w & 1) * 32;           // local row base within the 64-row pass
#pragma unroll
      for (int tr = 0; tr < 2; ++tr) {
        int rl = rl0 + tr * 16 + g * 4;
#pragma unroll
        for (int tc = 0; tc < 8; ++tc) {
          int col = tc * 16 + m;
#pragma unroll
          for (int e = 0; e < 4; ++e) sF[(rl + e) * 128 + col] = acc[tr][tc][e];
        }
#pragma unroll
        for (int e = 0; e < 4; ++e) {
          float v = acc[tr][8][e];
          if (m < 4) sAS[(rl + e) * 4 + m] = v;
          else if (m < 8) sAD[(rl + e) * 4 + (m - 4)] = v;
        }
      }
    }
    __syncthreads();
    const int base = blockIdx.x * 128 + pass * 64;
    for (int i = t; i < 64 * 32; i += 256) {   // full-line float4 stores
      int r = i >> 5, c4 = (i & 31) << 2;
      int gr = base + r;
      if (gr < N_NODES)
        *(float4*)&H[(size_t)gr * HF + c4] = *(const float4*)&sF[r * 128 + c4];
    }
    if (t < 64) {
      int gr = base + t;
      if (gr < N_NODES) *(float4*)&AS[(size_t)gr * 4] = *(const float4*)&sAS[t * 4];
    } else if (t < 128) {
      int gr = base + (t - 64);
      if (gr < N_NODES) *(float4*)&AD[(size_t)gr * 4] = *(const float4*)&sAD[(t - 64) * 4];
    }
  }
}

// ---------------- fused softmax + aggregation (R14 config — best known) ----
// Half-wave (32 lanes) per node; lane owns 4 cols (float4); unroll-4.
template<bool CONCAT>
__global__ void __launch_bounds__(256) k_aggregate(
    const int* __restrict__ rs, const int* __restrict__ csr_src,
    const float* __restrict__ H, const float* __restrict__ AS,
    const float* __restrict__ AD, const unsigned* __restrict__ M4,
    const float* __restrict__ bias, float* __restrict__ OUT) {
  int n = blockIdx.x * 8 + (threadIdx.x >> 5);
  if (n >= N_NODES) return;
  int sl = threadIdx.x & 31;
  int c = sl * 4;                      // this lane's 4 columns
  int head = sl >> 3;
  int b = rs[n], e = rs[n + 1];

  float ad = AD[4 * n + head];
  float m = lrelu(fdec(M4[head]) + ad);

  float ax = 0.f, ay = 0.f, az = 0.f, aw = 0.f, den = 0.f;
  int jj = b;
  for (; jj + 3 < e; jj += 4) {        // 4 gather chains in flight
    int s0 = csr_src[jj];
    int s1 = csr_src[jj + 1];
    int s2 = csr_src[jj + 2];
    int s3 = csr_src[jj + 3];
    float e0 = __expf(lrelu(AS[4 * s0 + head] + ad) - m);
    float e1 = __expf(lrelu(AS[4 * s1 + head] + ad) - m);
    float e2 = __expf(lrelu(AS[4 * s2 + head] + ad) - m);
    float e3 = __expf(lrelu(AS[4 * s3 + head] + ad) - m);
    float4 h0 = *(const float4*)&H[(size_t)s0 * HF + c];
    float4 h1 = *(const float4*)&H[(size_t)s1 * HF + c];
    float4 h2 = *(const float4*)&H[(size_t)s2 * HF + c];
    float4 h3 = *(const float4*)&H[(size_t)s3 * HF + c];
    ax += h0.x * e0 + h1.x * e1 + h2.x * e2 + h3.x * e3;
    ay += h0.y * e0 + h1.y * e1 + h2.y * e2 + h3.y * e3;
    az += h0.z * e0 + h1.z * e1 + h2.z * e2 + h3.z * e3;
    aw += h0.w * e0 + h1.w * e1 + h2.w * e2 + h3.w * e3;
    den += (e0 + e1) + (e2 + e3);
  }
  for (; jj < e; ++jj) {
    int s0 = csr_src[jj];
    float e0 = __expf(lrelu(AS[4 * s0 + head] + ad) - m);
    float4 h0 = *(const float4*)&H[(size_t)s0 * HF + c];
    ax += h0.x * e0; ay += h0.y * e0; az += h0.z * e0; aw += h0.w * e0;
    den += e0;
  }

  float invd = 1.f / den;
  if (CONCAT) {
    float4 o;
    o.x = elu_f(ax * invd + bias[c]);
    o.y = elu_f(ay * invd + bias[c + 1]);
    o.z = elu_f(az * invd + bias[c + 2]);
    o.w = elu_f(aw * invd + bias[c + 3]);
    *(float4*)&OUT[(size_t)n * HF + c] = o;
  } else {
    // mean over heads: fold lanes sl^8, sl^16 (stay within the 32-lane half)
    ax *= invd; ay *= invd; az *= invd; aw *= invd;
    ax += __shfl_xor(ax, 8);  ay += __shfl_xor(ay, 8);
    az += __shfl_xor(az, 8);  aw += __shfl_xor(aw, 8);
    ax += __shfl_xor(ax, 16); ay += __shfl_xor(ay, 16);
    az += __shfl_xor(az, 16); aw += __shfl_xor(aw, 16);
    if (sl < 8) {
      int cc = sl * 4;                 // 0..28
      float4 o;
      o.x = elu_f(0.25f * ax + bias[cc]);
      o.y = elu_f(0.25f * ay + bias[cc + 1]);
      o.z = elu_f(0.25f * az + bias[cc + 2]);
      o.w = elu_f(0.25f * aw + bias[cc + 3]);
      *(float4*)&OUT[(size_t)n * HID + cc] = o;
    }
  }
}

// ---------------- global mean pool + MLP head (one wave per graph) ----------------
__global__ void __launch_bounds__(64) k_pool_mlp(
    const int* __restrict__ batch, const float* __restrict__ H3,
    const float* __restrict__ Wm1, const float* __restrict__ bm1,
    const float* __restrict__ Wm2, const float* __restrict__ bm2,
    float* __restrict__ OUT) {
  int g = blockIdx.x;
  int t = threadIdx.x;
  __shared__ float pooled[HID];
  int lo = 0, hi = N_NODES;
  while (lo < hi) { int mid = (lo + hi) >> 1; if (batch[mid] < g) lo = mid + 1; else hi = mid; }
  int start = lo;
  hi = N_NODES;
  while (lo < hi) { int mid = (lo + hi) >> 1; if (batch[mid] < g + 1) lo = mid + 1; else hi = mid; }
  int end = lo;
  if (t < HID) {
    float s = 0.f;
    for (int n = start; n < end; ++n) s += H3[(size_t)n * HID + t];
    float cnt = (float)(end - start);
    pooled[t] = s / fmaxf(cnt, 1.f);
  }
  __syncthreads();
  float z = bm1[t];
#pragma unroll
  for (int f = 0; f < HID; ++f) z += pooled[f] * Wm1[f * 64 + t];
  z = fmaxf(z, 0.f);
  float p = z * Wm2[t];
  for (int off = 32; off > 0; off >>= 1) p += __shfl_down(p, off);
  if (t == 0) OUT[g] = p + bm2[0];
}

extern "C" void kernel_launch(void* const* d_in, const int* in_sizes, int n_in,
                              void* d_out, int out_size, void* d_ws, size_t ws_size,
                              hipStream_t stream) {
  const float* x    = (const float*)d_in[0];
  const int*   ei   = (const int*)d_in[1];
  const int*   batch= (const int*)d_in[2];
  const float* W1   = (const float*)d_in[3];
  const float* a1s  = (const float*)d_in[4];
  const float* a1d  = (const float*)d_in[5];
  const float* b1   = (const float*)d_in[6];
  const float* W2   = (const float*)d_in[7];
  const float* a2s  = (const float*)d_in[8];
  const float* a2d  = (const float*)d_in[9];
  const float* b2   = (const float*)d_in[10];
  const float* W3   = (const float*)d_in[11];
  const float* a3s  = (const float*)d_in[12];
  const float* a3d  = (const float*)d_in[13];
  const float* b3   = (const float*)d_in[14];
  const float* Wm1  = (const float*)d_in[15];
  const float* bm1  = (const float*)d_in[16];
  const float* Wm2  = (const float*)d_in[17];
  const float* bm2  = (const float*)d_in[18];
  float* out = (float*)d_out;

  char* p = (char*)d_ws;
  auto take = [&](size_t bytes) { char* r = p; p += (bytes + 255) & ~(size_t)255; return r; };
  float*          bufA = (float*)take((size_t)N_NODES * HF * 4);
  float*          bufB = (float*)take((size_t)N_NODES * HF * 4);
  float*          AS   = (float*)take((size_t)N_NODES * HEADS * 4);
  float*          AD   = (float*)take((size_t)N_NODES * HEADS * 4);
  unsigned*       M4   = (unsigned*)take(3 * 4 * 4);        // 3 layers x 4 heads
  int*            deg  = (int*)take((size_t)N_NODES * 4);   // reused as fill counters
  int*            rs   = (int*)take((size_t)(N_NODES + 1) * 4);
  int*            csr  = (int*)take((size_t)ET * 4);
  int*            bsums= (int*)take((size_t)512 * 4);
  unsigned short* Wh1  = (unsigned short*)take((size_t)IN_DIM * 144 * 2);
  unsigned short* Wl1  = (unsigned short*)take((size_t)IN_DIM * 144 * 2);
  unsigned short* Wh2  = (unsigned short*)take((size_t)HF * 144 * 2);
  unsigned short* Wl2  = (unsigned short*)take((size_t)HF * 144 * 2);
  unsigned short* Wh3  = (unsigned short*)take((size_t)HF * 144 * 2);
  unsigned short* Wl3  = (unsigned short*)take((size_t)HF * 144 * 2);

  unsigned* M4a = M4;
  unsigned* M4b = M4 + 4;
  unsigned* M4c = M4 + 8;

  const int nb_scan = (N_NODES + 255) / 256;  // 391

  // weight prep (independent of CSR; tiny)
  k_prep<IN_DIM><<<(IN_DIM * 144 + 255) / 256, 256, 0, stream>>>(W1, a1s, a1d, Wh1, Wl1);
  k_prep<HF><<<(HF * 144 + 255) / 256, 256, 0, stream>>>(W2, a2s, a2d, Wh2, Wl2);
  k_prep<HF><<<(HF * 144 + 255) / 256, 256, 0, stream>>>(W3, a3s, a3d, Wh3, Wl3);

  hipMemsetAsync(deg, 0, (size_t)N_NODES * 4, stream);
  hipMemsetAsync(M4, 0, 48, stream);
  k_count<<<(ET + 255) / 256, 256, 0, stream>>>(ei, deg);
  k_scan1<<<nb_scan, 256, 0, stream>>>(deg, rs, bsums);
  k_scan2<<<1, 512, 0, stream>>>(bsums, nb_scan);
  k_scan3<<<nb_scan, 256, 0, stream>>>(rs, bsums);
  hipMemsetAsync(deg, 0, (size_t)N_NODES * 4, stream);
  k_fill<<<(ET + 255) / 256, 256, 0, stream>>>(ei, rs, deg, csr);

  const int gb = (N_NODES + 127) / 128;       // 782 blocks of 128 rows
  const int ab = (N_NODES + 7) / 8;           // aggregate: 8 nodes/block

  // layer 1 (K=64)
  k_gemm_attn<IN_DIM><<<gb, 256, 0, stream>>>(x, Wh1, Wl1, bufA, AS, AD, M4a);
  k_aggregate<true><<<ab, 256, 0, stream>>>(rs, csr, bufA, AS, AD, M4a, b1, bufB);
  // layer 2 (K=128)
  k_gemm_attn<HF><<<gb, 256, 0, stream>>>(bufB, Wh2, Wl2, bufA, AS, AD, M4b);
  k_aggregate<true><<<ab, 256, 0, stream>>>(rs, csr, bufA, AS, AD, M4b, b2, bufB);
  // layer 3 (K=128, concat=False -> head mean)
  k_gemm_attn<HF><<<gb, 256, 0, stream>>>(bufB, Wh3, Wl3, bufA, AS, AD, M4c);
  k_aggregate<false><<<ab, 256, 0, stream>>>(rs, csr, bufA, AS, AD, M4c, b3, bufB);
  // pool + MLP
  k_pool_mlp<<<N_GRAPHS, 64, 0, stream>>>(batch, bufB, Wm1, bm1, Wm2, bm2, out);
}

// Round 17
// 453.328 us; speedup vs baseline: 1.1885x; 1.1885x over previous
//
#include <hip/hip_runtime.h>

#define N_NODES  100000
#define N_EDGES  800000
#define ET       900000   // edges + self loops
#define N_GRAPHS 2000
#define IN_DIM   64
#define HID      32
#define HEADS    4
#define HF       128      // HEADS*HID
#define NEG_SLOPE 0.2f

typedef __attribute__((ext_vector_type(8))) short bf16x8;
typedef __attribute__((ext_vector_type(4))) float f32x4;

__device__ __forceinline__ float lrelu(float x) { return x > 0.f ? x : NEG_SLOPE * x; }
__device__ __forceinline__ float elu_f(float x) { return x > 0.f ? x : expm1f(x); }
// order-preserving float<->uint encode for atomicMax over signed floats
__device__ __forceinline__ unsigned fenc(float f) {
  unsigned u = __float_as_uint(f);
  return (u & 0x80000000u) ? ~u : (u | 0x80000000u);
}
__device__ __forceinline__ float fdec(unsigned e) {
  return __uint_as_float((e & 0x80000000u) ? (e ^ 0x80000000u) : ~e);
}
// round-to-nearest-even fp32 -> bf16 (bit trick)
__device__ __forceinline__ unsigned short bf16_rne(float f) {
  unsigned u = __float_as_uint(f);
  unsigned r = (u + 0x7fffu + ((u >> 16) & 1u)) >> 16;
  return (unsigned short)r;
}

// ---------------- CSR build ----------------
__global__ void k_count(const int* __restrict__ ei, int* __restrict__ deg) {
  int e = blockIdx.x * 256 + threadIdx.x;
  if (e >= ET) return;
  int d = (e < N_EDGES) ? ei[N_EDGES + e] : (e - N_EDGES);
  atomicAdd(&deg[d], 1);
}

__global__ void k_scan1(const int* __restrict__ deg, int* __restrict__ rs, int* __restrict__ bsums) {
  __shared__ int sd[256];
  int t = threadIdx.x;
  int i = blockIdx.x * 256 + t;
  int v = (i < N_NODES) ? deg[i] : 0;
  sd[t] = v; __syncthreads();
  for (int s = 1; s < 256; s <<= 1) {
    int tmp = (t >= s) ? sd[t - s] : 0; __syncthreads();
    sd[t] += tmp; __syncthreads();
  }
  if (i < N_NODES) rs[i] = sd[t] - v;
  if (t == 255) bsums[blockIdx.x] = sd[255];
}

__global__ void k_scan2(int* __restrict__ bsums, int nb) {
  __shared__ int sd[512];
  int t = threadIdx.x;
  int v = (t < nb) ? bsums[t] : 0;
  sd[t] = v; __syncthreads();
  for (int s = 1; s < 512; s <<= 1) {
    int tmp = (t >= s) ? sd[t - s] : 0; __syncthreads();
    sd[t] += tmp; __syncthreads();
  }
  if (t < nb) bsums[t] = sd[t] - v;
}

__global__ void k_scan3(int* __restrict__ rs, const int* __restrict__ bsums) {
  int i = blockIdx.x * 256 + threadIdx.x;
  if (i < N_NODES) rs[i] += bsums[blockIdx.x];
  if (i == 0) rs[N_NODES] = ET;
}

__global__ void k_fill(const int* __restrict__ ei, const int* __restrict__ rs,
                       int* __restrict__ fill, int* __restrict__ csr_src) {
  int e = blockIdx.x * 256 + threadIdx.x;
  if (e >= ET) return;
  int s, d;
  if (e < N_EDGES) { s = ei[e]; d = ei[N_EDGES + e]; }
  else             { s = e - N_EDGES; d = s; }
  int pos = atomicAdd(&fill[d], 1);
  csr_src[rs[d] + pos] = s;
}

// ---------------- weight prep: pack [W | W.a_src | W.a_dst | 0] (144 cols),
// split fp32 -> bf16 hi/lo, store in MFMA B-fragment layout [k/8][c][k&7] ----
template<int K>
__global__ void k_prep(const float* __restrict__ W, const float* __restrict__ as_,
                       const float* __restrict__ ad_,
                       unsigned short* __restrict__ Bh, unsigned short* __restrict__ Bl) {
  int idx = blockIdx.x * 256 + threadIdx.x;
  if (idx >= K * 144) return;
  int k = idx / 144, c = idx % 144;
  float v = 0.f;
  if (c < 128) {
    v = W[k * 128 + c];
  } else if (c < 136) {
    int h = (c - 128) & 3;
    const float* av = (c < 132) ? as_ : ad_;
    float s = 0.f;
    for (int f = 0; f < HID; ++f) s += W[k * 128 + h * HID + f] * av[h * HID + f];
    v = s;
  }
  unsigned short hi = bf16_rne(v);
  float hf = __uint_as_float((unsigned)hi << 16);
  unsigned short lo = bf16_rne(v - hf);
  size_t dst = ((size_t)(k >> 3) * 144 + c) * 8 + (k & 7);
  Bh[dst] = hi;
  Bl[dst] = lo;
}

// ---------------- MFMA GEMM (split-bf16) + fused attention cols + AS max ----
// R14 config (best known) + G12-compliant max reduction: per-block LDS
// atomicMax then 4 global atomics per BLOCK (was 4 per WAVE — ~25K
// same-cache-line device atomics per dispatch, suspected hidden serializer).
template<int K>
__global__ void __launch_bounds__(256, 4) k_gemm_attn(
    const float* __restrict__ X,
    const unsigned short* __restrict__ Bh, const unsigned short* __restrict__ Bl,
    float* __restrict__ H, float* __restrict__ AS, float* __restrict__ AD,
    unsigned* __restrict__ M4) {
  constexpr unsigned BB = K * 144 * 2;               // bytes per B buffer
  constexpr unsigned FB = 128 * 128 * 4 + 128 * 8 * 4;  // bounce tile + AS/AD
  constexpr unsigned SM = (2 * BB > FB) ? 2 * BB : FB;
  __shared__ __align__(16) char smem[SM];
  __shared__ unsigned smax[HEADS];
  short* sBh = (short*)smem;
  short* sBl = (short*)(smem + BB);
  const int t = threadIdx.x;
  const int l = t & 63;
  const int w = t >> 6;
  const int m = l & 15;                 // A-row / B-col / D-col selector
  const int g = l >> 4;                 // k-group selector (8 k per group)
  const int row0 = blockIdx.x * 128 + w * 32;  // this wave's 32 rows
  const int row_a = row0 + m;           // tr=0 A row
  const int row_b = row0 + 16 + m;      // tr=1 A row

  if (t < HEADS) smax[t] = 0;           // covered by the staging barrier

  // one-time cooperative stage of the whole pre-fragmented B
  for (int i = t; i < K * 18; i += 256) {
    ((bf16x8*)sBh)[i] = ((const bf16x8*)Bh)[i];
    ((bf16x8*)sBl)[i] = ((const bf16x8*)Bl)[i];
  }
  __syncthreads();

  f32x4 acc[2][9];
#pragma unroll
  for (int a = 0; a < 2; ++a)
#pragma unroll
    for (int b = 0; b < 9; ++b) acc[a][b] = (f32x4){0.f, 0.f, 0.f, 0.f};

  float4 pxa0, pxb0, pxa1, pxb1;        // prefetched A (2 row-tiles x 32B)
#define LOADA(kb)                                                              \
  {                                                                            \
    pxa0 = pxb0 = pxa1 = pxb1 = make_float4(0.f, 0.f, 0.f, 0.f);               \
    if (row_a < N_NODES) {                                                     \
      const float4* xp = (const float4*)&X[(size_t)row_a * K + (kb) + g * 8];  \
      pxa0 = xp[0]; pxb0 = xp[1];                                              \
    }                                                                          \
    if (row_b < N_NODES) {                                                     \
      const float4* xp = (const float4*)&X[(size_t)row_b * K + (kb) + g * 8];  \
      pxa1 = xp[0]; pxb1 = xp[1];                                              \
    }                                                                          \
  }

  LOADA(0);
  for (int kb = 0; kb < K; kb += 32) {
    // convert the prefetched A to hi/lo bf16 fragments
    bf16x8 ahi[2], alo[2];
    {
      float xv0[8] = {pxa0.x, pxa0.y, pxa0.z, pxa0.w, pxb0.x, pxb0.y, pxb0.z, pxb0.w};
      float xv1[8] = {pxa1.x, pxa1.y, pxa1.z, pxa1.w, pxb1.x, pxb1.y, pxb1.z, pxb1.w};
#pragma unroll
      for (int j = 0; j < 8; ++j) {
        unsigned short h0 = bf16_rne(xv0[j]);
        ahi[0][j] = (short)h0;
        alo[0][j] = (short)bf16_rne(xv0[j] - __uint_as_float((unsigned)h0 << 16));
        unsigned short h1 = bf16_rne(xv1[j]);
        ahi[1][j] = (short)h1;
        alo[1][j] = (short)bf16_rne(xv1[j] - __uint_as_float((unsigned)h1 << 16));
      }
    }
    if (kb + 32 < K) LOADA(kb + 32);   // issue next chunk's loads now

    // B fragments from LDS, 3-product MFMA per (tr, tc)
    const int kfl = ((kb >> 3) + g) * 144;
#pragma unroll
    for (int tc = 0; tc < 9; ++tc) {
      bf16x8 bh = *(const bf16x8*)(sBh + (kfl + tc * 16 + m) * 8);
      bf16x8 bl = *(const bf16x8*)(sBl + (kfl + tc * 16 + m) * 8);
#pragma unroll
      for (int tr = 0; tr < 2; ++tr) {
        acc[tr][tc] = __builtin_amdgcn_mfma_f32_16x16x32_bf16(ahi[tr], bh, acc[tr][tc], 0, 0, 0);
        acc[tr][tc] = __builtin_amdgcn_mfma_f32_16x16x32_bf16(ahi[tr], bl, acc[tr][tc], 0, 0, 0);
        acc[tr][tc] = __builtin_amdgcn_mfma_f32_16x16x32_bf16(alo[tr], bh, acc[tr][tc], 0, 0, 0);
      }
    }
  }
#undef LOADA

  // per-head AS max: fold within wave, then LDS atomic (block), global later
  float vmax = -3.4e38f;
#pragma unroll
  for (int tr = 0; tr < 2; ++tr)
#pragma unroll
    for (int e = 0; e < 4; ++e) vmax = fmaxf(vmax, acc[tr][8][e]);
  vmax = fmaxf(vmax, __shfl_xor(vmax, 16));
  vmax = fmaxf(vmax, __shfl_xor(vmax, 32));
  if (g == 0 && m < 4) atomicMax(&smax[m], fenc(vmax));

  // ---- LDS bounce: D-layout scatter goes to LDS; global stores coalesced ---
  __syncthreads();                      // B ds_reads + smax updates complete
  if (t < HEADS) atomicMax(&M4[t], smax[t]);   // 4 global atomics per BLOCK
  float* sF  = (float*)smem;            // [128][128] fp32 tile
  float* sAS = sF + 128 * 128;          // [128][4]
  float* sAD = sAS + 128 * 4;           // [128][4]
  const int wrow0 = w * 32;
#pragma unroll
  for (int tr = 0; tr < 2; ++tr) {
    int rl = wrow0 + tr * 16 + g * 4;   // local row base for this lane
#pragma unroll
    for (int tc = 0; tc < 8; ++tc) {
      int col = tc * 16 + m;
#pragma unroll
      for (int e = 0; e < 4; ++e) sF[(rl + e) * 128 + col] = acc[tr][tc][e];
    }
#pragma unroll
    for (int e = 0; e < 4; ++e) {
      float v = acc[tr][8][e];
      if (m < 4) sAS[(rl + e) * 4 + m] = v;
      else if (m < 8) sAD[(rl + e) * 4 + (m - 4)] = v;
    }
  }
  __syncthreads();
  const int base = blockIdx.x * 128;
  for (int i = t; i < 128 * 32; i += 256) {     // full-line float4 stores
    int r = i >> 5, c4 = (i & 31) << 2;
    int gr = base + r;
    if (gr < N_NODES)
      *(float4*)&H[(size_t)gr * HF + c4] = *(const float4*)&sF[r * 128 + c4];
  }
  {
    int r = t & 127, gr = base + r;
    if (gr < N_NODES) {
      if (t < 128) *(float4*)&AS[(size_t)gr * 4] = *(const float4*)&sAS[r * 4];
      else         *(float4*)&AD[(size_t)gr * 4] = *(const float4*)&sAD[r * 4];
    }
  }
}

// ---------------- fused softmax + aggregation (R14 config — best known) ----
// Half-wave (32 lanes) per node; lane owns 4 cols (float4); unroll-4.
template<bool CONCAT>
__global__ void __launch_bounds__(256) k_aggregate(
    const int* __restrict__ rs, const int* __restrict__ csr_src,
    const float* __restrict__ H, const float* __restrict__ AS,
    const float* __restrict__ AD, const unsigned* __restrict__ M4,
    const float* __restrict__ bias, float* __restrict__ OUT) {
  int n = blockIdx.x * 8 + (threadIdx.x >> 5);
  if (n >= N_NODES) return;
  int sl = threadIdx.x & 31;
  int c = sl * 4;                      // this lane's 4 columns
  int head = sl >> 3;
  int b = rs[n], e = rs[n + 1];

  float ad = AD[4 * n + head];
  float m = lrelu(fdec(M4[head]) + ad);

  float ax = 0.f, ay = 0.f, az = 0.f, aw = 0.f, den = 0.f;
  int jj = b;
  for (; jj + 3 < e; jj += 4) {        // 4 gather chains in flight
    int s0 = csr_src[jj];
    int s1 = csr_src[jj + 1];
    int s2 = csr_src[jj + 2];
    int s3 = csr_src[jj + 3];
    float e0 = __expf(lrelu(AS[4 * s0 + head] + ad) - m);
    float e1 = __expf(lrelu(AS[4 * s1 + head] + ad) - m);
    float e2 = __expf(lrelu(AS[4 * s2 + head] + ad) - m);
    float e3 = __expf(lrelu(AS[4 * s3 + head] + ad) - m);
    float4 h0 = *(const float4*)&H[(size_t)s0 * HF + c];
    float4 h1 = *(const float4*)&H[(size_t)s1 * HF + c];
    float4 h2 = *(const float4*)&H[(size_t)s2 * HF + c];
    float4 h3 = *(const float4*)&H[(size_t)s3 * HF + c];
    ax += h0.x * e0 + h1.x * e1 + h2.x * e2 + h3.x * e3;
    ay += h0.y * e0 + h1.y * e1 + h2.y * e2 + h3.y * e3;
    az += h0.z * e0 + h1.z * e1 + h2.z * e2 + h3.z * e3;
    aw += h0.w * e0 + h1.w * e1 + h2.w * e2 + h3.w * e3;
    den += (e0 + e1) + (e2 + e3);
  }
  for (; jj < e; ++jj) {
    int s0 = csr_src[jj];
    float e0 = __expf(lrelu(AS[4 * s0 + head] + ad) - m);
    float4 h0 = *(const float4*)&H[(size_t)s0 * HF + c];
    ax += h0.x * e0; ay += h0.y * e0; az += h0.z * e0; aw += h0.w * e0;
    den += e0;
  }

  float invd = 1.f / den;
  if (CONCAT) {
    float4 o;
    o.x = elu_f(ax * invd + bias[c]);
    o.y = elu_f(ay * invd + bias[c + 1]);
    o.z = elu_f(az * invd + bias[c + 2]);
    o.w = elu_f(aw * invd + bias[c + 3]);
    *(float4*)&OUT[(size_t)n * HF + c] = o;
  } else {
    // mean over heads: fold lanes sl^8, sl^16 (stay within the 32-lane half)
    ax *= invd; ay *= invd; az *= invd; aw *= invd;
    ax += __shfl_xor(ax, 8);  ay += __shfl_xor(ay, 8);
    az += __shfl_xor(az, 8);  aw += __shfl_xor(aw, 8);
    ax += __shfl_xor(ax, 16); ay += __shfl_xor(ay, 16);
    az += __shfl_xor(az, 16); aw += __shfl_xor(aw, 16);
    if (sl < 8) {
      int cc = sl * 4;                 // 0..28
      float4 o;
      o.x = elu_f(0.25f * ax + bias[cc]);
      o.y = elu_f(0.25f * ay + bias[cc + 1]);
      o.z = elu_f(0.25f * az + bias[cc + 2]);
      o.w = elu_f(0.25f * aw + bias[cc + 3]);
      *(float4*)&OUT[(size_t)n * HID + cc] = o;
    }
  }
}

// ---------------- global mean pool + MLP head (one wave per graph) ----------------
__global__ void __launch_bounds__(64) k_pool_mlp(
    const int* __restrict__ batch, const float* __restrict__ H3,
    const float* __restrict__ Wm1, const float* __restrict__ bm1,
    const float* __restrict__ Wm2, const float* __restrict__ bm2,
    float* __restrict__ OUT) {
  int g = blockIdx.x;
  int t = threadIdx.x;
  __shared__ float pooled[HID];
  int lo = 0, hi = N_NODES;
  while (lo < hi) { int mid = (lo + hi) >> 1; if (batch[mid] < g) lo = mid + 1; else hi = mid; }
  int start = lo;
  hi = N_NODES;
  while (lo < hi) { int mid = (lo + hi) >> 1; if (batch[mid] < g + 1) lo = mid + 1; else hi = mid; }
  int end = lo;
  if (t < HID) {
    float s = 0.f;
    for (int n = start; n < end; ++n) s += H3[(size_t)n * HID + t];
    float cnt = (float)(end - start);
    pooled[t] = s / fmaxf(cnt, 1.f);
  }
  __syncthreads();
  float z = bm1[t];
#pragma unroll
  for (int f = 0; f < HID; ++f) z += pooled[f] * Wm1[f * 64 + t];
  z = fmaxf(z, 0.f);
  float p = z * Wm2[t];
  for (int off = 32; off > 0; off >>= 1) p += __shfl_down(p, off);
  if (t == 0) OUT[g] = p + bm2[0];
}

extern "C" void kernel_launch(void* const* d_in, const int* in_sizes, int n_in,
                              void* d_out, int out_size, void* d_ws, size_t ws_size,
                              hipStream_t stream) {
  const float* x    = (const float*)d_in[0];
  const int*   ei   = (const int*)d_in[1];
  const int*   batch= (const int*)d_in[2];
  const float* W1   = (const float*)d_in[3];
  const float* a1s  = (const float*)d_in[4];
  const float* a1d  = (const float*)d_in[5];
  const float* b1   = (const float*)d_in[6];
  const float* W2   = (const float*)d_in[7];
  const float* a2s  = (const float*)d_in[8];
  const float* a2d  = (const float*)d_in[9];
  const float* b2   = (const float*)d_in[10];
  const float* W3   = (const float*)d_in[11];
  const float* a3s  = (const float*)d_in[12];
  const float* a3d  = (const float*)d_in[13];
  const float* b3   = (const float*)d_in[14];
  const float* Wm1  = (const float*)d_in[15];
  const float* bm1  = (const float*)d_in[16];
  const float* Wm2  = (const float*)d_in[17];
  const float* bm2  = (const float*)d_in[18];
  float* out = (float*)d_out;

  char* p = (char*)d_ws;
  auto take = [&](size_t bytes) { char* r = p; p += (bytes + 255) & ~(size_t)255; return r; };
  float*          bufA = (float*)take((size_t)N_NODES * HF * 4);
  float*          bufB = (float*)take((size_t)N_NODES * HF * 4);
  float*          AS   = (float*)take((size_t)N_NODES * HEADS * 4);
  float*          AD   = (float*)take((size_t)N_NODES * HEADS * 4);
  unsigned*       M4   = (unsigned*)take(3 * 128);          // 3 layers, 128B apart
  int*            deg  = (int*)take((size_t)N_NODES * 4);   // reused as fill counters
  int*            rs   = (int*)take((size_t)(N_NODES + 1) * 4);
  int*            csr  = (int*)take((size_t)ET * 4);
  int*            bsums= (int*)take((size_t)512 * 4);
  unsigned short* Wh1  = (unsigned short*)take((size_t)IN_DIM * 144 * 2);
  unsigned short* Wl1  = (unsigned short*)take((size_t)IN_DIM * 144 * 2);
  unsigned short* Wh2  = (unsigned short*)take((size_t)HF * 144 * 2);
  unsigned short* Wl2  = (unsigned short*)take((size_t)HF * 144 * 2);
  unsigned short* Wh3  = (unsigned short*)take((size_t)HF * 144 * 2);
  unsigned short* Wl3  = (unsigned short*)take((size_t)HF * 144 * 2);

  unsigned* M4a = M4;
  unsigned* M4b = M4 + 32;              // 128 B apart: no shared cache line
  unsigned* M4c = M4 + 64;

  const int nb_scan = (N_NODES + 255) / 256;  // 391

  // weight prep (independent of CSR; tiny)
  k_prep<IN_DIM><<<(IN_DIM * 144 + 255) / 256, 256, 0, stream>>>(W1, a1s, a1d, Wh1, Wl1);
  k_prep<HF><<<(HF * 144 + 255) / 256, 256, 0, stream>>>(W2, a2s, a2d, Wh2, Wl2);
  k_prep<HF><<<(HF * 144 + 255) / 256, 256, 0, stream>>>(W3, a3s, a3d, Wh3, Wl3);

  hipMemsetAsync(deg, 0, (size_t)N_NODES * 4, stream);
  hipMemsetAsync(M4, 0, 3 * 128, stream);
  k_count<<<(ET + 255) / 256, 256, 0, stream>>>(ei, deg);
  k_scan1<<<nb_scan, 256, 0, stream>>>(deg, rs, bsums);
  k_scan2<<<1, 512, 0, stream>>>(bsums, nb_scan);
  k_scan3<<<nb_scan, 256, 0, stream>>>(rs, bsums);
  hipMemsetAsync(deg, 0, (size_t)N_NODES * 4, stream);
  k_fill<<<(ET + 255) / 256, 256, 0, stream>>>(ei, rs, deg, csr);

  const int gb = (N_NODES + 127) / 128;       // 782 blocks of 128 rows
  const int ab = (N_NODES + 7) / 8;           // aggregate: 8 nodes/block

  // layer 1 (K=64)
  k_gemm_attn<IN_DIM><<<gb, 256, 0, stream>>>(x, Wh1, Wl1, bufA, AS, AD, M4a);
  k_aggregate<true><<<ab, 256, 0, stream>>>(rs, csr, bufA, AS, AD, M4a, b1, bufB);
  // layer 2 (K=128)
  k_gemm_attn<HF><<<gb, 256, 0, stream>>>(bufB, Wh2, Wl2, bufA, AS, AD, M4b);
  k_aggregate<true><<<ab, 256, 0, stream>>>(rs, csr, bufA, AS, AD, M4b, b2, bufB);
  // layer 3 (K=128, concat=False -> head mean)
  k_gemm_attn<HF><<<gb, 256, 0, stream>>>(bufB, Wh3, Wl3, bufA, AS, AD, M4c);
  k_aggregate<false><<<ab, 256, 0, stream>>>(rs, csr, bufA, AS, AD, M4c, b3, bufB);
  // pool + MLP
  k_pool_mlp<<<N_GRAPHS, 64, 0, stream>>>(batch, bufB, Wm1, bm1, Wm2, bm2, out);
}